// Round 1
// baseline (234.006 us; speedup 1.0000x reference)
//
#include <hip/hip_runtime.h>
#include <hip/hip_bf16.h>
#include <cstdint>

#define EL 1048576ull   // 1Mi elements

typedef __bf16 bf16_t;
typedef bf16_t bf16x8 __attribute__((ext_vector_type(8)));
typedef float  f32x4  __attribute__((ext_vector_type(4)));

__device__ __forceinline__ unsigned short f2bf(float f) {
  unsigned int u = __builtin_bit_cast(unsigned int, f);
  u += 0x7FFFu + ((u >> 16) & 1u);   // RNE
  return (unsigned short)(u >> 16);
}

typedef __attribute__((address_space(1))) void as1_void;
typedef __attribute__((address_space(3))) void as3_void;
__device__ __forceinline__ void load_lds16(const void* g, void* l) {
  __builtin_amdgcn_global_load_lds((as1_void*)g, (as3_void*)l, 16, 0, 0);
}

__device__ __forceinline__ float redmax16(float v) {
  v = fmaxf(v, __shfl_xor(v, 1));
  v = fmaxf(v, __shfl_xor(v, 2));
  v = fmaxf(v, __shfl_xor(v, 4));
  v = fmaxf(v, __shfl_xor(v, 8));
  return v;
}
__device__ __forceinline__ float redsum16(float v) {
  v += __shfl_xor(v, 1);
  v += __shfl_xor(v, 2);
  v += __shfl_xor(v, 4);
  v += __shfl_xor(v, 8);
  return v;
}

// ---------------------------------------------------------------- convert
__global__ __launch_bounds__(256) void convert_all(
    const float* __restrict__ q, const float* __restrict__ k, const float* __restrict__ v,
    const float* __restrict__ wq, const float* __restrict__ wk,
    const float* __restrict__ wv, const float* __restrict__ wo,
    unsigned short* __restrict__ ws)
{
  const size_t total_v4 = 4 * EL; // 16M elems / 4
  for (size_t v4 = (size_t)blockIdx.x * blockDim.x + threadIdx.x; v4 < total_v4;
       v4 += (size_t)gridDim.x * blockDim.x) {
    size_t e = v4 * 4;
    unsigned seg = (unsigned)(e >> 20);
    const float* s; size_t base;
    if      (seg < 4)   { s = q;  base = 0; }
    else if (seg < 8)   { s = k;  base = 4*EL; }
    else if (seg < 12)  { s = v;  base = 8*EL; }
    else if (seg == 12) { s = wq; base = 12*EL; }
    else if (seg == 13) { s = wk; base = 13*EL; }
    else if (seg == 14) { s = wv; base = 14*EL; }
    else                { s = wo; base = 15*EL; }
    const float4 f = *(const float4*)(s + (e - base));
    ushort4 o;
    o.x = f2bf(f.x); o.y = f2bf(f.y); o.z = f2bf(f.z); o.w = f2bf(f.w);
    *(ushort4*)(ws + e) = o;
  }
}

// ---------------------------------------------------------------- GEMM C = A * B^T + bias
// A: [M][1024] bf16, B: [1024][1024] bf16 (row n holds B[n][k]), C: [M][1024]
template <int OUT_BF16>
__device__ __forceinline__ void gemm_bt_core(
    const unsigned short* __restrict__ A,
    const unsigned short* __restrict__ B,
    const float* __restrict__ bias,
    void* __restrict__ C)
{
  constexpr int K = 1024, N = 1024, BK = 32;
  __shared__ unsigned short sA[128 * BK];
  __shared__ unsigned short sB[128 * BK];
  const int tid  = threadIdx.x;
  const int wave = tid >> 6, lane = tid & 63;
  const int wm = wave >> 1, wn = wave & 1;
  const int tm = blockIdx.y * 128, tn = blockIdx.x * 128;
  const int l16 = lane & 15, lk8 = (lane >> 4) * 8, lr4 = (lane >> 4) * 4;

  f32x4 acc[4][4] = {};

  for (int k0 = 0; k0 < K; k0 += BK) {
    __syncthreads();
#pragma unroll
    for (int i = 0; i < 2; i++) {
      int idx = i * 256 + tid;
      int row = idx >> 2, col = (idx & 3) * 8;
      load_lds16(A + (size_t)(tm + row) * K + k0 + col, &sA[(i * 256 + wave * 64) * 8]);
    }
#pragma unroll
    for (int i = 0; i < 2; i++) {
      int idx = i * 256 + tid;
      int row = idx >> 2, col = (idx & 3) * 8;
      load_lds16(B + (size_t)(tn + row) * K + k0 + col, &sB[(i * 256 + wave * 64) * 8]);
    }
    __syncthreads();

    bf16x8 af[4], bfr[4];
#pragma unroll
    for (int i = 0; i < 4; i++)
      af[i] = *(const bf16x8*)&sA[(wm * 64 + i * 16 + l16) * BK + lk8];
#pragma unroll
    for (int j = 0; j < 4; j++)
      bfr[j] = *(const bf16x8*)&sB[(wn * 64 + j * 16 + l16) * BK + lk8];
#pragma unroll
    for (int i = 0; i < 4; i++)
#pragma unroll
      for (int j = 0; j < 4; j++)
        acc[i][j] = __builtin_amdgcn_mfma_f32_16x16x32_bf16(af[i], bfr[j], acc[i][j], 0, 0, 0);
  }

#pragma unroll
  for (int i = 0; i < 4; i++) {
    int row0 = tm + wm * 64 + i * 16 + lr4;
#pragma unroll
    for (int j = 0; j < 4; j++) {
      int col = tn + wn * 64 + j * 16 + l16;
      float bv = bias[col];
#pragma unroll
      for (int r = 0; r < 4; r++) {
        float val = acc[i][j][r] + bv;
        if (OUT_BF16) ((unsigned short*)C)[(size_t)(row0 + r) * N + col] = f2bf(val);
        else          ((float*)C)[(size_t)(row0 + r) * N + col] = val;
      }
    }
  }
}

__global__ __launch_bounds__(256, 2) void qkv_gemm(
    const unsigned short* qb, const unsigned short* kb, const unsigned short* vb,
    const unsigned short* wqb, const unsigned short* wkb, const unsigned short* wvb,
    const float* bq, const float* bk, const float* bv,
    unsigned short* Qp, unsigned short* Kp, unsigned short* Vp)
{
  const unsigned short* A; const unsigned short* B; const float* bias; unsigned short* C;
  if (blockIdx.z == 0)      { A = qb; B = wqb; bias = bq; C = Qp; }
  else if (blockIdx.z == 1) { A = kb; B = wkb; bias = bk; C = Kp; }
  else                      { A = vb; B = wvb; bias = bv; C = Vp; }
  gemm_bt_core<1>(A, B, bias, C);
}

__global__ __launch_bounds__(256, 2) void out_gemm(
    const unsigned short* Yb, const unsigned short* wob, const float* bo, float* out)
{
  gemm_bt_core<0>(Yb, wob, bo, out);
}

// ---------------------------------------------------------------- flash attention
// Qp/Kp/Vp: [(b*S+s)][1024] bf16 ; per block: one (b,h) pair, 128 q-rows.
__global__ __launch_bounds__(256, 2) void attn_kernel(
    const unsigned short* __restrict__ Qp, const unsigned short* __restrict__ Kp,
    const unsigned short* __restrict__ Vp, const int* __restrict__ mask,
    unsigned short* __restrict__ Yb)
{
  constexpr int S = 2048, H = 1024;
  __shared__ unsigned short sK[128 * 64];    // K tile (also Q staging)
  __shared__ unsigned short sVt[64 * 128];   // V tile transposed [d][kv]
  __shared__ unsigned short sP[4 * 32 * 128];

  const int tid = threadIdx.x, wave = tid >> 6, lane = tid & 63;
  const int l16 = lane & 15, lk8 = (lane >> 4) * 8, lr4 = (lane >> 4) * 4;
  const int qt = blockIdx.x * 128;
  const int h = blockIdx.y, b = blockIdx.z;
  const size_t hb = (size_t)b * S * H + (size_t)h * 64;
  const unsigned short* Qb = Qp + hb;
  const unsigned short* Kb = Kp + hb;
  const unsigned short* Vb = Vp + hb;
  const int* mrow = mask + (size_t)b * S;

  // ---- stage Q tile (128x64) into sK, pull fragments to registers
#pragma unroll
  for (int i = 0; i < 4; i++) {
    int idx = i * 256 + tid;
    int row = idx >> 3, col = (idx & 7) * 8;
    load_lds16(Qb + (size_t)(qt + row) * H + col, &sK[(i * 256 + wave * 64) * 8]);
  }
  __syncthreads();
  bf16x8 qf[2][2];
#pragma unroll
  for (int m = 0; m < 2; m++)
#pragma unroll
    for (int ks = 0; ks < 2; ks++)
      qf[m][ks] = *(const bf16x8*)&sK[(wave * 32 + m * 16 + l16) * 64 + ks * 32 + lk8];

  // per-q-row mask (reference masks along the QUERY axis)
  float qmask[2][4];
#pragma unroll
  for (int m = 0; m < 2; m++)
#pragma unroll
    for (int r = 0; r < 4; r++)
      qmask[m][r] = (float)mrow[qt + wave * 32 + m * 16 + lr4 + r];
  __syncthreads();

  float mrun[2][4], lrun[2][4];
  f32x4 oacc[2][4] = {};
#pragma unroll
  for (int m = 0; m < 2; m++)
#pragma unroll
    for (int r = 0; r < 4; r++) { mrun[m][r] = -3.0e38f; lrun[m][r] = 0.f; }

  for (int kv0 = 0; kv0 < S; kv0 += 128) {
    // stage K tile
#pragma unroll
    for (int i = 0; i < 4; i++) {
      int idx = i * 256 + tid;
      int row = idx >> 3, col = (idx & 7) * 8;
      load_lds16(Kb + (size_t)(kv0 + row) * H + col, &sK[(i * 256 + wave * 64) * 8]);
    }
    // stage V transposed: sVt[d][kv]
#pragma unroll
    for (int i = 0; i < 8; i++) {
      int v4 = i * 256 + tid;
      int r = v4 & 127, c4 = v4 >> 7;
      const unsigned int* gp = (const unsigned int*)(Vb + (size_t)(kv0 + r) * H + c4 * 4);
      unsigned int u0 = gp[0], u1 = gp[1];
      sVt[(c4 * 4 + 0) * 128 + r] = (unsigned short)u0;
      sVt[(c4 * 4 + 1) * 128 + r] = (unsigned short)(u0 >> 16);
      sVt[(c4 * 4 + 2) * 128 + r] = (unsigned short)u1;
      sVt[(c4 * 4 + 3) * 128 + r] = (unsigned short)(u1 >> 16);
    }
    __syncthreads();

    // scores: S = Q K^T
    f32x4 sf[2][8] = {};
#pragma unroll
    for (int j = 0; j < 8; j++) {
      bf16x8 kf0 = *(const bf16x8*)&sK[(j * 16 + l16) * 64 + lk8];
      bf16x8 kf1 = *(const bf16x8*)&sK[(j * 16 + l16) * 64 + 32 + lk8];
#pragma unroll
      for (int m = 0; m < 2; m++) {
        sf[m][j] = __builtin_amdgcn_mfma_f32_16x16x32_bf16(qf[m][0], kf0, sf[m][j], 0, 0, 0);
        sf[m][j] = __builtin_amdgcn_mfma_f32_16x16x32_bf16(qf[m][1], kf1, sf[m][j], 0, 0, 0);
      }
    }

    // scale + query-mask + row max
    float rmax[2][4];
#pragma unroll
    for (int m = 0; m < 2; m++)
#pragma unroll
      for (int r = 0; r < 4; r++) rmax[m][r] = -3.0e38f;
#pragma unroll
    for (int m = 0; m < 2; m++)
#pragma unroll
      for (int j = 0; j < 8; j++)
#pragma unroll
        for (int r = 0; r < 4; r++) {
          float val = sf[m][j][r] * 0.125f;
          val = (qmask[m][r] != 0.f) ? val : -1.0e9f;
          sf[m][j][r] = val;
          rmax[m][r] = fmaxf(rmax[m][r], val);
        }
#pragma unroll
    for (int m = 0; m < 2; m++)
#pragma unroll
      for (int r = 0; r < 4; r++) rmax[m][r] = redmax16(rmax[m][r]);

    // online softmax update
    float psum[2][4];
#pragma unroll
    for (int m = 0; m < 2; m++)
#pragma unroll
      for (int r = 0; r < 4; r++) {
        float nm = fmaxf(mrun[m][r], rmax[m][r]);
        float sc = __expf(mrun[m][r] - nm);
        mrun[m][r] = nm;
        lrun[m][r] *= sc;
        psum[m][r] = 0.f;
#pragma unroll
        for (int n = 0; n < 4; n++) oacc[m][n][r] *= sc;
      }
#pragma unroll
    for (int m = 0; m < 2; m++)
#pragma unroll
      for (int j = 0; j < 8; j++)
#pragma unroll
        for (int r = 0; r < 4; r++) {
          float p = __expf(sf[m][j][r] - mrun[m][r]);
          sf[m][j][r] = p;
          psum[m][r] += p;
        }
#pragma unroll
    for (int m = 0; m < 2; m++)
#pragma unroll
      for (int r = 0; r < 4; r++) lrun[m][r] += redsum16(psum[m][r]);

    // write P (bf16) to per-wave LDS region
    unsigned short* pw = &sP[wave * 32 * 128];
#pragma unroll
    for (int m = 0; m < 2; m++)
#pragma unroll
      for (int j = 0; j < 8; j++)
#pragma unroll
        for (int r = 0; r < 4; r++)
          pw[(m * 16 + lr4 + r) * 128 + j * 16 + l16] = f2bf(sf[m][j][r]);

    // PV
#pragma unroll
    for (int ks = 0; ks < 4; ks++) {
      bf16x8 pf[2];
#pragma unroll
      for (int m = 0; m < 2; m++)
        pf[m] = *(const bf16x8*)&pw[(m * 16 + l16) * 128 + ks * 32 + lk8];
#pragma unroll
      for (int n = 0; n < 4; n++) {
        bf16x8 vf = *(const bf16x8*)&sVt[(n * 16 + l16) * 128 + ks * 32 + lk8];
#pragma unroll
        for (int m = 0; m < 2; m++)
          oacc[m][n] = __builtin_amdgcn_mfma_f32_16x16x32_bf16(pf[m], vf, oacc[m][n], 0, 0, 0);
      }
    }
    __syncthreads();
  }

  // epilogue: O / l  -> Yb
#pragma unroll
  for (int m = 0; m < 2; m++)
#pragma unroll
    for (int n = 0; n < 4; n++)
#pragma unroll
      for (int r = 0; r < 4; r++) {
        int row = qt + wave * 32 + m * 16 + lr4 + r;
        int col = n * 16 + l16;
        float val = oacc[m][n][r] / lrun[m][r];
        Yb[((size_t)b * S + row) * H + h * 64 + col] = f2bf(val);
      }
}

// ---------------------------------------------------------------- launch
extern "C" void kernel_launch(void* const* d_in, const int* in_sizes, int n_in,
                              void* d_out, int out_size, void* d_ws, size_t ws_size,
                              hipStream_t stream)
{
  const float* q  = (const float*)d_in[0];
  const float* k  = (const float*)d_in[1];
  const float* v  = (const float*)d_in[2];
  const int*  mask = (const int*)d_in[3];
  const float* Wq = (const float*)d_in[4];
  const float* bq = (const float*)d_in[5];
  const float* Wk = (const float*)d_in[6];
  const float* bk = (const float*)d_in[7];
  const float* Wv = (const float*)d_in[8];
  const float* bv = (const float*)d_in[9];
  const float* Wo = (const float*)d_in[10];
  const float* bo = (const float*)d_in[11];

  unsigned short* ws  = (unsigned short*)d_ws;
  unsigned short* qb  = ws;
  unsigned short* kb  = ws + 4 * EL;
  unsigned short* vb  = ws + 8 * EL;
  unsigned short* wqb = ws + 12 * EL;
  unsigned short* wkb = ws + 13 * EL;
  unsigned short* wvb = ws + 14 * EL;
  unsigned short* wob = ws + 15 * EL;
  unsigned short* Qp  = ws + 16 * EL;
  unsigned short* Kp  = ws + 20 * EL;
  unsigned short* Vp  = ws + 24 * EL;
  unsigned short* Yb  = ws + 28 * EL;

  convert_all<<<2048, 256, 0, stream>>>(q, k, v, Wq, Wk, Wv, Wo, ws);
  qkv_gemm<<<dim3(8, 32, 3), 256, 0, stream>>>(qb, kb, vb, wqb, wkb, wvb,
                                               bq, bk, bv, Qp, Kp, Vp);
  attn_kernel<<<dim3(16, 16, 2), 256, 0, stream>>>(Qp, Kp, Vp, mask, Yb);
  out_gemm<<<dim3(8, 32), 256, 0, stream>>>(Yb, wob, bo, (float*)d_out);
}

// Round 2
// 158.567 us; speedup vs baseline: 1.4758x; 1.4758x over previous
//
#include <hip/hip_runtime.h>
#include <hip/hip_bf16.h>
#include <cstdint>

#define EL 1048576ull   // 1Mi elements

typedef __bf16 bf16_t;
typedef bf16_t bf16x8 __attribute__((ext_vector_type(8)));
typedef float  f32x4  __attribute__((ext_vector_type(4)));
typedef unsigned int u32x4 __attribute__((ext_vector_type(4)));

__device__ __forceinline__ unsigned short f2bf(float f) {
  unsigned int u = __builtin_bit_cast(unsigned int, f);
  u += 0x7FFFu + ((u >> 16) & 1u);   // RNE
  return (unsigned short)(u >> 16);
}
__device__ __forceinline__ unsigned int pk2(float lo, float hi2) {
  return (unsigned int)f2bf(lo) | ((unsigned int)f2bf(hi2) << 16);
}

typedef __attribute__((address_space(1))) void as1_void;
typedef __attribute__((address_space(3))) void as3_void;
__device__ __forceinline__ void load_lds16(const void* g, void* l) {
  __builtin_amdgcn_global_load_lds((as1_void*)g, (as3_void*)l, 16, 0, 0);
}

// ---------------------------------------------------------------- convert
__global__ __launch_bounds__(256) void convert_all(
    const float* __restrict__ q, const float* __restrict__ k, const float* __restrict__ v,
    const float* __restrict__ wq, const float* __restrict__ wk,
    const float* __restrict__ wv, const float* __restrict__ wo,
    unsigned short* __restrict__ ws)
{
  const size_t total_v4 = 4 * EL; // 16M elems / 4
  for (size_t v4 = (size_t)blockIdx.x * blockDim.x + threadIdx.x; v4 < total_v4;
       v4 += (size_t)gridDim.x * blockDim.x) {
    size_t e = v4 * 4;
    unsigned seg = (unsigned)(e >> 20);
    const float* s; size_t base;
    if      (seg < 4)   { s = q;  base = 0; }
    else if (seg < 8)   { s = k;  base = 4*EL; }
    else if (seg < 12)  { s = v;  base = 8*EL; }
    else if (seg == 12) { s = wq; base = 12*EL; }
    else if (seg == 13) { s = wk; base = 13*EL; }
    else if (seg == 14) { s = wv; base = 14*EL; }
    else                { s = wo; base = 15*EL; }
    const float4 f = *(const float4*)(s + (e - base));
    ushort4 o;
    o.x = f2bf(f.x); o.y = f2bf(f.y); o.z = f2bf(f.z); o.w = f2bf(f.w);
    *(ushort4*)(ws + e) = o;
  }
}

// ---------------------------------------------------------------- GEMM C = A * B^T + bias
// A: [M][1024] bf16, B: [1024][1024] bf16 (row n holds B[n][k]), C: [M][N=1024]
// BK=64, XOR-swizzled LDS (granule ^= row&7), staged via pre-swizzled global src.
template <int BM, int BN, int WM, int WN, int OUT_BF16>
__device__ __forceinline__ void gemm_bt_core(
    const unsigned short* __restrict__ A,
    const unsigned short* __restrict__ B,
    const float* __restrict__ bias,
    void* __restrict__ C)
{
  constexpr int K = 1024, N = 1024, BK = 64;
  constexpr int AM = BM / WM / 16, AN = BN / WN / 16;
  __shared__ unsigned short sA[BM * BK];
  __shared__ unsigned short sB[BN * BK];
  const int tid  = threadIdx.x;
  const int wave = tid >> 6, lane = tid & 63;
  const int wm = wave / WN, wn = wave % WN;
  const int tm = blockIdx.y * BM, tn = blockIdx.x * BN;
  const int l16 = lane & 15, hi = lane >> 4, swz = l16 & 7;

  f32x4 acc[AM][AN] = {};

  for (int k0 = 0; k0 < K; k0 += BK) {
    __syncthreads();
#pragma unroll
    for (int i = 0; i < BM * 8 / 256; i++) {
      int p = i * 256 + tid;
      int row = p >> 3, c = p & 7;
      load_lds16(A + (size_t)(tm + row) * K + k0 + ((c ^ (row & 7)) * 8),
                 &sA[(i * 256 + wave * 64) * 8]);
    }
#pragma unroll
    for (int i = 0; i < BN * 8 / 256; i++) {
      int p = i * 256 + tid;
      int row = p >> 3, c = p & 7;
      load_lds16(B + (size_t)(tn + row) * K + k0 + ((c ^ (row & 7)) * 8),
                 &sB[(i * 256 + wave * 64) * 8]);
    }
    __syncthreads();

#pragma unroll
    for (int kk = 0; kk < 2; kk++) {
      bf16x8 af[AM], bfr[AN];
#pragma unroll
      for (int i = 0; i < AM; i++) {
        int row = wm * (BM / WM) + i * 16 + l16;
        af[i] = *(const bf16x8*)&sA[row * BK + (((kk * 4 + hi) ^ swz) * 8)];
      }
#pragma unroll
      for (int j = 0; j < AN; j++) {
        int row = wn * (BN / WN) + j * 16 + l16;
        bfr[j] = *(const bf16x8*)&sB[row * BK + (((kk * 4 + hi) ^ swz) * 8)];
      }
#pragma unroll
      for (int i = 0; i < AM; i++)
#pragma unroll
        for (int j = 0; j < AN; j++)
          acc[i][j] = __builtin_amdgcn_mfma_f32_16x16x32_bf16(af[i], bfr[j], acc[i][j], 0, 0, 0);
    }
  }

#pragma unroll
  for (int i = 0; i < AM; i++) {
    int row0 = tm + wm * (BM / WM) + i * 16 + hi * 4;
#pragma unroll
    for (int j = 0; j < AN; j++) {
      int col = tn + wn * (BN / WN) + j * 16 + l16;
      float bv = bias[col];
#pragma unroll
      for (int r = 0; r < 4; r++) {
        float val = acc[i][j][r] + bv;
        if (OUT_BF16) ((unsigned short*)C)[(size_t)(row0 + r) * N + col] = f2bf(val);
        else          ((float*)C)[(size_t)(row0 + r) * N + col] = val;
      }
    }
  }
}

__global__ __launch_bounds__(256, 3) void qkv_gemm(
    const unsigned short* qb, const unsigned short* kb, const unsigned short* vb,
    const unsigned short* wqb, const unsigned short* wkb, const unsigned short* wvb,
    const float* bq, const float* bk, const float* bv,
    unsigned short* Qp, unsigned short* Kp, unsigned short* Vp)
{
  const unsigned short* A; const unsigned short* B; const float* bias; unsigned short* C;
  if (blockIdx.z == 0)      { A = qb; B = wqb; bias = bq; C = Qp; }
  else if (blockIdx.z == 1) { A = kb; B = wkb; bias = bk; C = Kp; }
  else                      { A = vb; B = wvb; bias = bv; C = Vp; }
  gemm_bt_core<128, 128, 2, 2, 1>(A, B, bias, C);
}

__global__ __launch_bounds__(256, 2) void out_gemm(
    const unsigned short* Yb, const unsigned short* wob, const float* bo, float* out)
{
  gemm_bt_core<128, 64, 4, 1, 0>(Yb, wob, bo, out);
}

// ---------------------------------------------------------------- flash attention
// Swapped QK^T (S^T = mfma(K,Q)) -> lane-local softmax, in-register P repack.
// 8 waves x 16 q-rows = 128 q-rows per block. LDS: swizzled K (16K) + V^T (16K).
__global__ __launch_bounds__(512, 4) void attn_kernel(
    const unsigned short* __restrict__ Qp, const unsigned short* __restrict__ Kp,
    const unsigned short* __restrict__ Vp, const int* __restrict__ mask,
    unsigned short* __restrict__ Yb)
{
  constexpr int S = 2048, H = 1024;
  __shared__ unsigned short sK[128 * 64];    // K tile (also Q staging), swizzled
  __shared__ unsigned short sVt[64 * 128];   // V tile transposed [d][kv], swizzled

  const int tid = threadIdx.x, wave = tid >> 6, lane = tid & 63;
  const int l16 = lane & 15, hi = lane >> 4, swz = l16 & 7;
  const int qt = blockIdx.x * 128;
  const int h = blockIdx.y, b = blockIdx.z;
  const size_t hb = (size_t)b * S * H + (size_t)h * 64;
  const unsigned short* Qb = Qp + hb;
  const unsigned short* Kb = Kp + hb;
  const unsigned short* Vb = Vp + hb;

  // ---- stage Q tile (128x64) swizzled into sK
#pragma unroll
  for (int i = 0; i < 2; i++) {
    int p = i * 512 + tid;               // 16B granule id (8 shorts)
    int row = p >> 3, c = p & 7;
    load_lds16(Qb + (size_t)(qt + row) * H + ((c ^ (row & 7)) * 8),
               &sK[(i * 512 + wave * 64) * 8]);
  }
  __syncthreads();
  bf16x8 qf[2];
#pragma unroll
  for (int ks = 0; ks < 2; ks++) {
    int row = wave * 16 + l16;
    qf[ks] = *(const bf16x8*)&sK[row * 64 + (((ks * 4 + hi) ^ swz) * 8)];
  }
  // per-lane q-row mask (reference masks along the QUERY axis)
  const float qm = (float)mask[(size_t)b * S + qt + wave * 16 + l16];
  __syncthreads();

  float mrun = -3.0e38f, lrun = 0.f;
  f32x4 oacc[4] = {};

  for (int kv0 = 0; kv0 < S; kv0 += 128) {
    // stage K tile swizzled (pre-swizzled global source, linear LDS dest)
#pragma unroll
    for (int i = 0; i < 2; i++) {
      int p = i * 512 + tid;
      int row = p >> 3, c = p & 7;
      load_lds16(Kb + (size_t)(kv0 + row) * H + ((c ^ (row & 7)) * 8),
                 &sK[(i * 512 + wave * 64) * 8]);
    }
    // stage V transposed+swizzled: sVt[d][kv], granule (kv>>3)^(d&7)
#pragma unroll
    for (int i = 0; i < 2; i++) {
      int v8 = i * 512 + tid;            // 8-short chunk
      int kv = v8 & 127, c8 = v8 >> 7;
      const u32x4 u = *(const u32x4*)(Vb + (size_t)(kv0 + kv) * H + c8 * 8);
#pragma unroll
      for (int e = 0; e < 8; e++) {
        int d = c8 * 8 + e;
        unsigned short val = (unsigned short)(u[e >> 1] >> ((e & 1) * 16));
        sVt[d * 128 + (((kv >> 3) ^ (d & 7)) * 8) + (kv & 7)] = val;
      }
    }
    __syncthreads();

    // ---- QK^T swapped: sf[j] = S^T frag; lane holds q = l16, kv = j*16 + hi*4 + r
    f32x4 sf[8] = {};
#pragma unroll
    for (int j = 0; j < 8; j++) {
      int row = j * 16 + l16;
      bf16x8 kf0 = *(const bf16x8*)&sK[row * 64 + ((hi ^ swz) * 8)];
      bf16x8 kf1 = *(const bf16x8*)&sK[row * 64 + (((4 + hi) ^ swz) * 8)];
      sf[j] = __builtin_amdgcn_mfma_f32_16x16x32_bf16(kf0, qf[0], sf[j], 0, 0, 0);
      sf[j] = __builtin_amdgcn_mfma_f32_16x16x32_bf16(kf1, qf[1], sf[j], 0, 0, 0);
    }

    // ---- scale + query-mask + lane-local max
    float rm = -3.0e38f;
#pragma unroll
    for (int j = 0; j < 8; j++)
#pragma unroll
      for (int r = 0; r < 4; r++) {
        float val = sf[j][r] * 0.125f;
        val = (qm != 0.f) ? val : -1.0e9f;
        sf[j][r] = val;
        rm = fmaxf(rm, val);
      }
    rm = fmaxf(rm, __shfl_xor(rm, 16));
    rm = fmaxf(rm, __shfl_xor(rm, 32));

    float nm = fmaxf(mrun, rm);
    float sc = __expf(mrun - nm);
    mrun = nm;

    float ps = 0.f;
#pragma unroll
    for (int j = 0; j < 8; j++)
#pragma unroll
      for (int r = 0; r < 4; r++) {
        float p = __expf(sf[j][r] - mrun);
        sf[j][r] = p;
        ps += p;
      }
    ps += __shfl_xor(ps, 16);
    ps += __shfl_xor(ps, 32);
    lrun = lrun * sc + ps;

    // redistribute rescale factor to oacc's q-rows (q_local = hi*4+r lives at lane l16=q)
    float scr[4];
#pragma unroll
    for (int r = 0; r < 4; r++) scr[r] = __shfl(sc, hi * 4 + r);
#pragma unroll
    for (int n = 0; n < 4; n++)
#pragma unroll
      for (int r = 0; r < 4; r++) oacc[n][r] *= scr[r];

    // ---- P repack (in-register) + PV, per 32-kv window
#pragma unroll
    for (int w = 0; w < 4; w++) {
      unsigned int c00 = pk2(sf[2 * w][0],     sf[2 * w][1]);
      unsigned int c01 = pk2(sf[2 * w][2],     sf[2 * w][3]);
      unsigned int c10 = pk2(sf[2 * w + 1][0], sf[2 * w + 1][1]);
      unsigned int c11 = pk2(sf[2 * w + 1][2], sf[2 * w + 1][3]);
      u32x4 wd;
#pragma unroll
      for (int t = 0; t < 4; t++) {
        int src = l16 + 16 * ((hi & 1) * 2 + (t >> 1));
        unsigned int s0 = (unsigned int)__shfl((int)((t & 1) ? c01 : c00), src);
        unsigned int s1 = (unsigned int)__shfl((int)((t & 1) ? c11 : c10), src);
        wd[t] = (hi >> 1) ? s1 : s0;
      }
      bf16x8 af = __builtin_bit_cast(bf16x8, wd);
#pragma unroll
      for (int n = 0; n < 4; n++) {
        int drow = n * 16 + l16;
        bf16x8 vf = *(const bf16x8*)&sVt[drow * 128 + (((w * 4 + hi) ^ swz) * 8)];
        oacc[n] = __builtin_amdgcn_mfma_f32_16x16x32_bf16(af, vf, oacc[n], 0, 0, 0);
      }
    }
    __syncthreads();
  }

  // ---- epilogue: O / l  -> Yb
  float lr[4];
#pragma unroll
  for (int r = 0; r < 4; r++) {
    float lv = __shfl(lrun, hi * 4 + r);
    lr[r] = 1.0f / lv;
  }
#pragma unroll
  for (int n = 0; n < 4; n++)
#pragma unroll
    for (int r = 0; r < 4; r++) {
      int row = qt + wave * 16 + hi * 4 + r;
      int col = n * 16 + l16;
      Yb[((size_t)b * S + row) * H + h * 64 + col] = f2bf(oacc[n][r] * lr[r]);
    }
}

// ---------------------------------------------------------------- launch
extern "C" void kernel_launch(void* const* d_in, const int* in_sizes, int n_in,
                              void* d_out, int out_size, void* d_ws, size_t ws_size,
                              hipStream_t stream)
{
  const float* q  = (const float*)d_in[0];
  const float* k  = (const float*)d_in[1];
  const float* v  = (const float*)d_in[2];
  const int*  mask = (const int*)d_in[3];
  const float* Wq = (const float*)d_in[4];
  const float* bq = (const float*)d_in[5];
  const float* Wk = (const float*)d_in[6];
  const float* bk = (const float*)d_in[7];
  const float* Wv = (const float*)d_in[8];
  const float* bv = (const float*)d_in[9];
  const float* Wo = (const float*)d_in[10];
  const float* bo = (const float*)d_in[11];

  unsigned short* ws  = (unsigned short*)d_ws;
  unsigned short* qb  = ws;
  unsigned short* kb  = ws + 4 * EL;
  unsigned short* vb  = ws + 8 * EL;
  unsigned short* wqb = ws + 12 * EL;
  unsigned short* wkb = ws + 13 * EL;
  unsigned short* wvb = ws + 14 * EL;
  unsigned short* wob = ws + 15 * EL;
  unsigned short* Qp  = ws + 16 * EL;
  unsigned short* Kp  = ws + 20 * EL;
  unsigned short* Vp  = ws + 24 * EL;
  unsigned short* Yb  = ws + 28 * EL;

  convert_all<<<2048, 256, 0, stream>>>(q, k, v, Wq, Wk, Wv, Wo, ws);
  qkv_gemm<<<dim3(8, 32, 3), 256, 0, stream>>>(qb, kb, vb, wqb, wkb, wvb,
                                               bq, bk, bv, Qp, Kp, Vp);
  attn_kernel<<<dim3(16, 16, 2), 512, 0, stream>>>(Qp, Kp, Vp, mask, Yb);
  out_gemm<<<dim3(16, 32), 256, 0, stream>>>(Yb, wob, bo, (float*)d_out);
}